// Round 9
// baseline (932.789 us; speedup 1.0000x reference)
//
#include <hip/hip_runtime.h>

// ArDCA loss: loss = -sum_{m,i} W[m] * log_softmax(h[i,:] + sum_{j<i} J[i,j,:,X[m,j]])[X[m,i]]
//             + 1e-6 * sum h^2 + 1e-4 * sum_{j<i} J^2
// M=8192, L=256, Q=21. Output: single fp32 scalar.
//
// R9: R8's software pipeline with R6's proven-safe bounds.
// R8 crashed on an OOB: JC=12 made the unconditional int4 X-loads read up to
// index j0+15 = 263 > 255 on the last chunk (past X for the final row).
// JC=16 keeps j0 <= 240 -> X reads end exactly at 255, in-bounds always
// (the R1-R7 invariant). NROWS=336: tid owns row tid; tid<80 also owns
// row tid+256 (R6 ownership).
// Pipeline: iter c = [issue global loads chunk c+1 into regs]
// [gather chunk c from buf c&1] [pack+write c+1 -> buf (c+1)&1] [barrier]
// - one barrier per chunk, staging load latency covered by the gather phase.
// MPT=2 (grid 4096 ~ 2 residency rounds; R7 showed 1 round collapses).
// bf8(e5m2) LDS tiles: unpack = v_perm (f16 = bf8<<8, exact), accumulate =
// v_pk_add_f16, full-rate. Scale x64 at pack, x1/64 in epilogue. Reg terms
// folded into blockIdx.x==0 staging on exact fp32 values.
// dur_us carries ~110us harness constant on top of the pair dispatch.

#define M_SEQ 8192
#define L_POS 256
#define Q_SYM 21
#define QQ    441
#define JC    16
#define NROWS (JC * Q_SYM)       // 336 rows per chunk
#define MPT   2                  // m's per thread

typedef _Float16 half2v __attribute__((ext_vector_type(2)));

__device__ __forceinline__ half2v h2_from_u32(unsigned u) {
    union { unsigned u; half2v h; } c; c.u = u; return c.h;
}

// pack 4 floats to 4 e5m2 bytes
__device__ __forceinline__ unsigned pack4_bf8(float a, float b, float c, float d) {
    int w = __builtin_amdgcn_cvt_pk_bf8_f32(a, b, 0, false);   // bytes 0,1
    w = __builtin_amdgcn_cvt_pk_bf8_f32(c, d, w, true);        // bytes 2,3
    return (unsigned)w;
}

// dword of 4 e5m2 bytes -> two half2 (lo = bytes 0,1 ; hi = bytes 2,3)
// f16 = e5m2_byte << 8  (exact: same exponent bias, subnormals map)
__device__ __forceinline__ half2v bf8lo_h2(unsigned d) {
    return h2_from_u32(__builtin_amdgcn_perm(0u, d, 0x010C000Cu)); // [0,b0,0,b1]
}
__device__ __forceinline__ half2v bf8hi_h2(unsigned d) {
    return h2_from_u32(__builtin_amdgcn_perm(0u, d, 0x030C020Cu)); // [0,b2,0,b3]
}

// gather one row r from the bf8 tile and accumulate 21 values into acc[0..10]
__device__ __forceinline__ void gather_add(const float4* __restrict__ JA,
                                           const float2* __restrict__ JB,
                                           int r, half2v* acc) {
    float4 lo = JA[r];
    float2 hi = JB[r];
    unsigned d0 = __builtin_bit_cast(unsigned, lo.x);
    unsigned d1 = __builtin_bit_cast(unsigned, lo.y);
    unsigned d2 = __builtin_bit_cast(unsigned, lo.z);
    unsigned d3 = __builtin_bit_cast(unsigned, lo.w);
    unsigned d4 = __builtin_bit_cast(unsigned, hi.x);
    unsigned d5 = __builtin_bit_cast(unsigned, hi.y);
    acc[0]  += bf8lo_h2(d0);  acc[1]  += bf8hi_h2(d0);
    acc[2]  += bf8lo_h2(d1);  acc[3]  += bf8hi_h2(d1);
    acc[4]  += bf8lo_h2(d2);  acc[5]  += bf8hi_h2(d2);
    acc[6]  += bf8lo_h2(d3);  acc[7]  += bf8hi_h2(d3);
    acc[8]  += bf8lo_h2(d4);  acc[9]  += bf8hi_h2(d4);
    acc[10] += bf8lo_h2(d5);                       // (v20, 0)
}

// pack a staged row (v[21], fp32) to bf8 and write to buffer row;
// optionally accumulate sum(J^2) on the exact fp32 values.
__device__ __forceinline__ void stage_pack(const float* v, bool val, bool reg_on,
                                           float* regsum,
                                           float4* __restrict__ JA,
                                           float2* __restrict__ JB, int row) {
    if (!val) return;
    if (reg_on) {
        float rs = 0.0f;
        #pragma unroll
        for (int a = 0; a < Q_SYM; ++a) rs += v[a] * v[a];
        *regsum += rs;
    }
    const float SC = 64.0f;
    unsigned w0 = pack4_bf8(SC*v[0],  SC*v[1],  SC*v[2],  SC*v[3]);
    unsigned w1 = pack4_bf8(SC*v[4],  SC*v[5],  SC*v[6],  SC*v[7]);
    unsigned w2 = pack4_bf8(SC*v[8],  SC*v[9],  SC*v[10], SC*v[11]);
    unsigned w3 = pack4_bf8(SC*v[12], SC*v[13], SC*v[14], SC*v[15]);
    unsigned w4 = pack4_bf8(SC*v[16], SC*v[17], SC*v[18], SC*v[19]);
    unsigned w5 = (unsigned)__builtin_amdgcn_cvt_pk_bf8_f32(SC*v[20], 0.f, 0, false);
    JA[row] = make_float4(__builtin_bit_cast(float, w0),
                          __builtin_bit_cast(float, w1),
                          __builtin_bit_cast(float, w2),
                          __builtin_bit_cast(float, w3));
    JB[row] = make_float2(__builtin_bit_cast(float, w4),
                          __builtin_bit_cast(float, w5));
}

__device__ __forceinline__ float nll_one(const float* hrow, const half2v* acc,
                                         int g, float w) {
    const float INV = 1.0f / 64.0f;
    float logits[Q_SYM];
    #pragma unroll
    for (int k = 0; k < 10; ++k) {
        logits[2 * k]     = hrow[2 * k]     + (float)acc[k].x * INV;
        logits[2 * k + 1] = hrow[2 * k + 1] + (float)acc[k].y * INV;
    }
    logits[20] = hrow[20] + (float)acc[10].x * INV;

    float mx = -3.4e38f;
    #pragma unroll
    for (int a = 0; a < Q_SYM; ++a) mx = fmaxf(mx, logits[a]);
    float s = 0.0f;
    #pragma unroll
    for (int a = 0; a < Q_SYM; ++a) s += __expf(logits[a] - mx);
    float gold = 0.0f;
    #pragma unroll
    for (int a = 0; a < Q_SYM; ++a) gold = (a == g) ? logits[a] : gold;
    float logp = gold - mx - __logf(s);
    return -w * logp;
}

__device__ __forceinline__ float wave_block_reduce(float v, float* red, int tid) {
    #pragma unroll
    for (int off = 32; off > 0; off >>= 1) v += __shfl_down(v, off, 64);
    if ((tid & 63) == 0) red[tid >> 6] = v;
    __syncthreads();
    return red[0] + red[1] + red[2] + red[3];
}

__global__ void zero_out(float* __restrict__ out) { out[0] = 0.0f; }

// One block per (m-chunk of 512, i). Each thread owns 2 m's.
__global__ __launch_bounds__(256) void pair_nll_kernel(const int* __restrict__ X,
                                                       const float* __restrict__ W,
                                                       const float* __restrict__ h,
                                                       const float* __restrict__ J,
                                                       float* __restrict__ out) {
    __shared__ float4 JA[2][NROWS];   // 16 bf8 per row (vals 0..15)  2*5376 B
    __shared__ float2 JB[2][NROWS];   // 5 bf8 + pad    (vals 16..20) 2*2688 B
    __shared__ float red[4];

    const int tid = threadIdx.x;
    // interleave i across dispatch order for load balance (work ~ i)
    const int i  = ((blockIdx.y & 1) << 7) | (blockIdx.y >> 1);
    const int m0 = blockIdx.x * (256 * MPT) + tid;
    const bool do_reg = (blockIdx.x == 0);
    const int* xrow0 = X + (size_t)m0 * L_POS;
    const int* xrow1 = xrow0 + 256 * L_POS;

    // thread-owned staging rows (R6 ownership): row0 = tid; row1 = tid+256 (tid<80)
    const int jc0 = tid / Q_SYM;
    const int b0  = tid - jc0 * Q_SYM;
    const int row1 = tid + 256;
    const int jc1 = row1 / Q_SYM;
    const int b1  = row1 - jc1 * Q_SYM;
    const bool has_row1 = (row1 < NROWS);
    const float* Jb0 = J + ((size_t)i * L_POS + jc0) * QQ + b0;
    const float* Jb1 = J + ((size_t)i * L_POS + jc1) * QQ + b1;

    half2v acc[MPT][11];   // per m: 10 pairs + [10].x for value 20
    #pragma unroll
    for (int p = 0; p < MPT; ++p)
        #pragma unroll
        for (int k = 0; k < 11; ++k) { acc[p][k].x = (_Float16)0.f; acc[p][k].y = (_Float16)0.f; }
    float regsum = 0.0f;

    const int nch = (i + JC - 1) / JC;   // 0 when i == 0
    float v0[Q_SYM], v1[Q_SYM];

    if (nch > 0) {
        // ---- preheader: load + stage chunk 0 into buf 0
        bool val0 = (jc0 < i);
        bool val1 = has_row1 && (jc1 < i);
        if (val0) {
            #pragma unroll
            for (int a = 0; a < Q_SYM; ++a) v0[a] = Jb0[a * Q_SYM];
        }
        if (val1) {
            #pragma unroll
            for (int a = 0; a < Q_SYM; ++a) v1[a] = Jb1[a * Q_SYM];
        }
        stage_pack(v0, val0, do_reg && val0, &regsum, &JA[0][0], &JB[0][0], tid);
        stage_pack(v1, val1, do_reg && val1, &regsum, &JA[0][0], &JB[0][0], row1);
        __syncthreads();   // buf0 ready

        for (int c = 0; c < nch; ++c) {
            const int j0  = c * JC;
            const int cur = c & 1;
            // ---- issue global loads for chunk c+1 (latency covered by gather)
            bool nval0 = false, nval1 = false;
            if (c + 1 < nch) {
                const size_t off = (size_t)(j0 + JC) * QQ;
                nval0 = (j0 + JC + jc0 < i);
                nval1 = has_row1 && (j0 + JC + jc1 < i);
                if (nval0) {
                    #pragma unroll
                    for (int a = 0; a < Q_SYM; ++a) v0[a] = Jb0[off + (size_t)a * Q_SYM];
                }
                if (nval1) {
                    #pragma unroll
                    for (int a = 0; a < Q_SYM; ++a) v1[a] = Jb1[off + (size_t)a * Q_SYM];
                }
            }
            // ---- gather chunk c from buf[cur]
            // X reads: j0 <= 240, int4 groups end at index 255 -> in-bounds always
            #pragma unroll
            for (int g = 0; g < 4; ++g) {
                int4 x0 = *(const int4*)(xrow0 + j0 + 4 * g);
                int4 x1 = *(const int4*)(xrow1 + j0 + 4 * g);
                int a0[4] = {x0.x, x0.y, x0.z, x0.w};
                int a1[4] = {x1.x, x1.y, x1.z, x1.w};
                #pragma unroll
                for (int t = 0; t < 4; ++t) {
                    int jc = 4 * g + t;
                    if (j0 + jc < i) {             // block-uniform scalar branch
                        int rbase = jc * Q_SYM;
                        gather_add(&JA[cur][0], &JB[cur][0], rbase + a0[t], acc[0]);
                        gather_add(&JA[cur][0], &JB[cur][0], rbase + a1[t], acc[1]);
                    }
                }
            }
            // ---- pack+write chunk c+1 into the other buffer
            if (c + 1 < nch) {
                stage_pack(v0, nval0, do_reg && nval0, &regsum,
                           &JA[cur ^ 1][0], &JB[cur ^ 1][0], tid);
                stage_pack(v1, nval1, do_reg && nval1, &regsum,
                           &JA[cur ^ 1][0], &JB[cur ^ 1][0], row1);
            }
            __syncthreads();   // one barrier per chunk
        }
    }

    // ---- epilogue: 2 NLL terms + reg fold
    const float* hrow = h + i * Q_SYM;
    float vr = 0.0f;
    vr += nll_one(hrow, acc[0], xrow0[i], W[m0]);
    vr += nll_one(hrow, acc[1], xrow1[i], W[m0 + 256]);

    if (do_reg) {
        vr += 1e-4f * regsum;
        if (tid < Q_SYM) {
            float hv = hrow[tid];
            vr += 1e-6f * hv * hv;
        }
    }

    __syncthreads();   // LDS reuse safety before reduction
    float tot = wave_block_reduce(vr, red, tid);
    if (tid == 0) atomicAdd(out, tot);
}

extern "C" void kernel_launch(void* const* d_in, const int* in_sizes, int n_in,
                              void* d_out, int out_size, void* d_ws, size_t ws_size,
                              hipStream_t stream) {
    const int*   X = (const int*)d_in[0];
    const float* W = (const float*)d_in[1];
    const float* h = (const float*)d_in[2];
    const float* J = (const float*)d_in[3];
    float* out = (float*)d_out;

    hipLaunchKernelGGL(zero_out, dim3(1), dim3(1), 0, stream, out);
    dim3 grid(M_SEQ / (256 * MPT), L_POS);
    hipLaunchKernelGGL(pair_nll_kernel, grid, dim3(256), 0, stream, X, W, h, J, out);
}